// Round 2
// baseline (175.603 us; speedup 1.0000x reference)
//
#include <hip/hip_runtime.h>
#include <hip/hip_cooperative_groups.h>

// ChannelAttention b=2, n=4096, c=32 fp32.
// S = X X^T (Gram), softmax over j per row i, out[j,c] = sum_i attn[i,j] x[i,c]; out*g + x.
//
// R4 -> R5 (theory revision): measured dur_us ~= 81us of harness 256MiB
// workspace-poison fills (2 x 40.7us, visible as fillBufferAligned at 82% HBM
// peak in rocprof) + ~12us of our three kernels. The controllable region is
// the 12us. This round: fuse the 3 kernels into ONE cooperative kernel with
// grid.sync() between phases, removing 2 launch boundaries + 2 end-of-kernel
// wave drains. Phases are grid-stride so any co-resident grid is correct;
// grid sized via occupancy query; 3-kernel fallback kept.
//
// Math plan unchanged (16x16x32 f16 MFMA, K = c = 32):
//  phase0: convert x -> Xf16 [b][n][c] and XT f16 [b][c][n]
//  phase1: Z_i = sum_j exp(s_ij - 48); c2[i] = -log2(Z_i) - 48*log2e
//  phase2: per 16-j tile: S-MFMA -> attn = exp2(s*log2e + c2[i]) (fp16)
//          -> in-register quad shuffle (8x ds_bpermute + 4x cndmask) -> PV-MFMA.

namespace cg = cooperative_groups;

typedef _Float16 half8 __attribute__((ext_vector_type(8)));
typedef _Float16 half4v __attribute__((ext_vector_type(4)));
typedef _Float16 half2v __attribute__((ext_vector_type(2)));
typedef float float4v __attribute__((ext_vector_type(4)));
typedef int int4v __attribute__((ext_vector_type(4)));

#define NN 4096
#define CC 32
#define L2E 1.44269504f
#define SHIFT 48.0f

// ================= shared phase bodies =================

__device__ __forceinline__ void convert_body(int t, const float* __restrict__ x,
                                             _Float16* __restrict__ xf,
                                             _Float16* __restrict__ xt) {
    const int n  = t & 4095;
    const int cg_ = (t >> 12) & 7;
    const int b  = t >> 15;
    const int row = (b << 12) | n;
    const float4* src = (const float4*)(x + (size_t)row * CC + cg_ * 4);
    float4 v = *src;
    _Float16 h0 = (_Float16)v.x, h1 = (_Float16)v.y, h2 = (_Float16)v.z, h3 = (_Float16)v.w;
    *(half4v*)(xf + (size_t)row * CC + cg_ * 4) = (half4v){h0, h1, h2, h3};
    _Float16* xtb = xt + (size_t)b * CC * NN;
    xtb[(cg_ * 4 + 0) * NN + n] = h0;   // consecutive lanes -> consecutive n: coalesced
    xtb[(cg_ * 4 + 1) * NN + n] = h1;
    xtb[(cg_ * 4 + 2) * NN + n] = h2;
    xtb[(cg_ * 4 + 3) * NN + n] = h3;
}

// pass1 tile: one 16-row i-tile; 8 waves x 512 j each, 4 B-tiles/iter, 1-deep prefetch.
__device__ __forceinline__ void pass1_tile(int tile, int tid,
                                           const _Float16* __restrict__ xf,
                                           float* __restrict__ c2out,
                                           float (*zw)[16]) {
    const int wave = tid >> 6, lane = tid & 63;
    const int quad = lane >> 4, l15 = lane & 15;
    const int b = tile >> 8;
    const int i0 = (tile & 255) * 16;
    const _Float16* xb = xf + (size_t)b * NN * CC;

    const half8 afrag = *(const half8*)(xb + (size_t)(i0 + l15) * CC + quad * 8);
    const float4v zf = {0.f, 0.f, 0.f, 0.f};
    float z[4] = {0.f, 0.f, 0.f, 0.f};
    const float c2c = -SHIFT * L2E;

    const int jbase = wave * 512;
    half8 b0 = *(const half8*)(xb + (size_t)(jbase + l15) * CC + quad * 8);
    half8 b1 = *(const half8*)(xb + (size_t)(jbase + 16 + l15) * CC + quad * 8);
    half8 b2 = *(const half8*)(xb + (size_t)(jbase + 32 + l15) * CC + quad * 8);
    half8 b3 = *(const half8*)(xb + (size_t)(jbase + 48 + l15) * CC + quad * 8);

    for (int jt = 0; jt < 8; ++jt) {           // 8 iters x 4 tiles x 16 j = 512 j
        const int jn = jbase + ((jt + 1) & 7) * 64;   // wraps on last iter (harmless)
        half8 n0 = *(const half8*)(xb + (size_t)(jn + l15) * CC + quad * 8);
        half8 n1 = *(const half8*)(xb + (size_t)(jn + 16 + l15) * CC + quad * 8);
        half8 n2 = *(const half8*)(xb + (size_t)(jn + 32 + l15) * CC + quad * 8);
        half8 n3 = *(const half8*)(xb + (size_t)(jn + 48 + l15) * CC + quad * 8);

        float4v s0 = __builtin_amdgcn_mfma_f32_16x16x32_f16(afrag, b0, zf, 0, 0, 0);
        float4v s1 = __builtin_amdgcn_mfma_f32_16x16x32_f16(afrag, b1, zf, 0, 0, 0);
        float4v s2 = __builtin_amdgcn_mfma_f32_16x16x32_f16(afrag, b2, zf, 0, 0, 0);
        float4v s3 = __builtin_amdgcn_mfma_f32_16x16x32_f16(afrag, b3, zf, 0, 0, 0);
#pragma unroll
        for (int r = 0; r < 4; ++r) {
            z[r] += __builtin_amdgcn_exp2f(fmaf(s0[r], L2E, c2c));
            z[r] += __builtin_amdgcn_exp2f(fmaf(s1[r], L2E, c2c));
            z[r] += __builtin_amdgcn_exp2f(fmaf(s2[r], L2E, c2c));
            z[r] += __builtin_amdgcn_exp2f(fmaf(s3[r], L2E, c2c));
        }
        b0 = n0; b1 = n1; b2 = n2; b3 = n3;
    }
#pragma unroll
    for (int off = 1; off <= 8; off <<= 1) {
#pragma unroll
        for (int r = 0; r < 4; ++r) z[r] += __shfl_xor(z[r], off, 64);
    }
    if (l15 == 0) {
#pragma unroll
        for (int r = 0; r < 4; ++r) zw[wave][quad * 4 + r] = z[r];
    }
    __syncthreads();
    if (tid < 16) {
        float zs = 0.f;
#pragma unroll
        for (int w = 0; w < 8; ++w) zs += zw[w][tid];
        c2out[b * NN + i0 + tid] = -(__builtin_amdgcn_logf(zs) + SHIFT * L2E);
    }
}

// pass2 tile: one 16-j tile; wave w covers i in [w*512,(w+1)*512), 32 i/iter.
// C->A transpose in registers: 8x ds_bpermute + 4x cndmask (static permutation).
__device__ __forceinline__ void pass2_tile(int tile, int tid,
                                           const _Float16* __restrict__ xf,
                                           const _Float16* __restrict__ xt,
                                           const float* __restrict__ c2,
                                           const float* __restrict__ x,
                                           const float* __restrict__ gamma,
                                           float* __restrict__ out,
                                           float (*red)[16][32]) {
    const int wave = tid >> 6, lane = tid & 63;
    const int quad = lane >> 4, l15 = lane & 15;
    const int b = tile >> 8;
    const int j0 = (tile & 255) * 16;
    const _Float16* xb  = xf + (size_t)b * NN * CC;
    const _Float16* xtb = xt + (size_t)b * CC * NN;
    const float* c2b = c2 + b * NN;

    // bpermute byte addresses: A0/A1 pull from lane ((q&1)*32 + j15),
    // A2/A3 from lane ((q&1)*32 + 16 + j15). Select p0 (q<2) vs p1 (q>=2) data.
    const int addrLo = (((quad & 1) << 5) + l15) << 2;
    const int addrHi = addrLo + 64;
    const bool lo32 = (lane < 32);

    const half8 bjfrag = *(const half8*)(xb + (size_t)(j0 + l15) * CC + quad * 8);
    const float4v zf = {0.f, 0.f, 0.f, 0.f};
    float4v acc0 = zf, acc1 = zf;

    const int ibase = wave * 512;
    half8 a0  = *(const half8*)(xb + (size_t)(ibase + l15) * CC + quad * 8);
    half8 a1  = *(const half8*)(xb + (size_t)(ibase + 16 + l15) * CC + quad * 8);
    half8 xb0 = *(const half8*)(xtb + (size_t)l15 * NN + ibase + quad * 8);
    half8 xb1 = *(const half8*)(xtb + (size_t)(l15 + 16) * NN + ibase + quad * 8);
    float4v c20 = *(const float4v*)(c2b + ibase + quad * 4);
    float4v c21 = *(const float4v*)(c2b + ibase + 16 + quad * 4);

    for (int it = 0; it < 16; ++it) {
        const int inx = ibase + ((it + 1) & 15) * 32;   // wraps on last iter
        half8 na0  = *(const half8*)(xb + (size_t)(inx + l15) * CC + quad * 8);
        half8 na1  = *(const half8*)(xb + (size_t)(inx + 16 + l15) * CC + quad * 8);
        half8 nxb0 = *(const half8*)(xtb + (size_t)l15 * NN + inx + quad * 8);
        half8 nxb1 = *(const half8*)(xtb + (size_t)(l15 + 16) * NN + inx + quad * 8);
        float4v nc20 = *(const float4v*)(c2b + inx + quad * 4);
        float4v nc21 = *(const float4v*)(c2b + inx + 16 + quad * 4);

        float4v s0 = __builtin_amdgcn_mfma_f32_16x16x32_f16(a0, bjfrag, zf, 0, 0, 0);
        float4v s1 = __builtin_amdgcn_mfma_f32_16x16x32_f16(a1, bjfrag, zf, 0, 0, 0);
        float4v e0, e1;
#pragma unroll
        for (int r = 0; r < 4; ++r) {
            e0[r] = __builtin_amdgcn_exp2f(fmaf(s0[r], L2E, c20[r]));
            e1[r] = __builtin_amdgcn_exp2f(fmaf(s1[r], L2E, c21[r]));
        }
        const int d0 = __builtin_bit_cast(int, (half2v)__builtin_amdgcn_cvt_pkrtz(e0[0], e0[1]));
        const int d1 = __builtin_bit_cast(int, (half2v)__builtin_amdgcn_cvt_pkrtz(e0[2], e0[3]));
        const int d2 = __builtin_bit_cast(int, (half2v)__builtin_amdgcn_cvt_pkrtz(e1[0], e1[1]));
        const int d3 = __builtin_bit_cast(int, (half2v)__builtin_amdgcn_cvt_pkrtz(e1[2], e1[3]));
        const int q0 = __builtin_amdgcn_ds_bpermute(addrLo, d0);
        const int q1 = __builtin_amdgcn_ds_bpermute(addrLo, d1);
        const int q2 = __builtin_amdgcn_ds_bpermute(addrHi, d0);
        const int q3 = __builtin_amdgcn_ds_bpermute(addrHi, d1);
        const int q4 = __builtin_amdgcn_ds_bpermute(addrLo, d2);
        const int q5 = __builtin_amdgcn_ds_bpermute(addrLo, d3);
        const int q6 = __builtin_amdgcn_ds_bpermute(addrHi, d2);
        const int q7 = __builtin_amdgcn_ds_bpermute(addrHi, d3);
        int4v ai;
        ai[0] = lo32 ? q0 : q4;
        ai[1] = lo32 ? q1 : q5;
        ai[2] = lo32 ? q2 : q6;
        ai[3] = lo32 ? q3 : q7;
        const half8 a2 = __builtin_bit_cast(half8, ai);   // P^T[j=l15][i32=quad*8+t]

        acc0 = __builtin_amdgcn_mfma_f32_16x16x32_f16(a2, xb0, acc0, 0, 0, 0);
        acc1 = __builtin_amdgcn_mfma_f32_16x16x32_f16(a2, xb1, acc1, 0, 0, 0);

        a0 = na0; a1 = na1; xb0 = nxb0; xb1 = nxb1; c20 = nc20; c21 = nc21;
    }

#pragma unroll
    for (int r = 0; r < 4; ++r) {
        red[wave][quad * 4 + r][l15]      = acc0[r];
        red[wave][quad * 4 + r][l15 + 16] = acc1[r];
    }
    __syncthreads();
    {
        const int jj = tid >> 5, c = tid & 31;   // 512 threads = 16 j x 32 c
        float s = 0.f;
#pragma unroll
        for (int w = 0; w < 8; ++w) s += red[w][jj][c];
        const float g = gamma[0];
        const size_t o = (size_t)(b * NN + j0 + jj) * CC + c;
        out[o] = fmaf(g, s, x[o]);
    }
}

// ================= fused cooperative kernel =================

__global__ __launch_bounds__(512, 4) void k_fused(const float* __restrict__ x,
                                                  const float* __restrict__ gamma,
                                                  _Float16* __restrict__ xf,
                                                  _Float16* __restrict__ xt,
                                                  float* __restrict__ c2,
                                                  float* __restrict__ out) {
    cg::grid_group grid = cg::this_grid();
    const int tid = threadIdx.x;
    const int nb = gridDim.x;

    __shared__ float zw[8][16];
    __shared__ float red[8][16][32];

    // phase 0: convert (65536 work items of 4 channels each)
    for (int t = blockIdx.x * 512 + tid; t < 65536; t += nb * 512)
        convert_body(t, x, xf, xt);
    grid.sync();

    // phase 1: row sums -> c2
    for (int tile = blockIdx.x; tile < 512; tile += nb) {
        pass1_tile(tile, tid, xf, c2, zw);
        __syncthreads();   // protect zw reuse if multiple tiles per block
    }
    grid.sync();

    // phase 2: output
    for (int tile = blockIdx.x; tile < 512; tile += nb) {
        pass2_tile(tile, tid, xf, xt, c2, x, gamma, out, red);
        __syncthreads();   // protect red reuse if multiple tiles per block
    }
}

// ================= fallback 3-kernel path =================

__global__ __launch_bounds__(256) void k_convert(const float* __restrict__ x,
                                                 _Float16* __restrict__ xf,
                                                 _Float16* __restrict__ xt) {
    const int t = blockIdx.x * 256 + threadIdx.x;
    convert_body(t, x, xf, xt);
}

__global__ __launch_bounds__(512, 4) void k_pass1(const _Float16* __restrict__ xf,
                                                  float* __restrict__ c2out) {
    __shared__ float zw[8][16];
    pass1_tile(blockIdx.x, threadIdx.x, xf, c2out, zw);
}

__global__ __launch_bounds__(512, 4) void k_pass2(const _Float16* __restrict__ xf,
                                                  const _Float16* __restrict__ xt,
                                                  const float* __restrict__ c2,
                                                  const float* __restrict__ x,
                                                  const float* __restrict__ gamma,
                                                  float* __restrict__ out) {
    __shared__ float red[8][16][32];
    pass2_tile(blockIdx.x, threadIdx.x, xf, xt, c2, x, gamma, out, red);
}

extern "C" void kernel_launch(void* const* d_in, const int* in_sizes, int n_in,
                              void* d_out, int out_size, void* d_ws, size_t ws_size,
                              hipStream_t stream) {
    const float* x     = (const float*)d_in[0];
    const float* gamma = (const float*)d_in[1];
    float* out = (float*)d_out;

    // ws layout: Xf16 (512 KB) | XT f16 (512 KB) | c2 fp32 (32 KB)
    _Float16* xf = (_Float16*)d_ws;
    _Float16* xt = xf + (size_t)2 * NN * CC;
    float*    c2 = (float*)(xt + (size_t)2 * CC * NN);

    int coopAttr = 0;
    (void)hipDeviceGetAttribute(&coopAttr, hipDeviceAttributeCooperativeLaunch, 0);
    int occ = 0;
    hipError_t oe = hipOccupancyMaxActiveBlocksPerMultiprocessor(&occ, k_fused, 512, 0);

    if (coopAttr && oe == hipSuccess && occ > 0) {
        int grid = occ * 256;
        if (grid > 512) grid = 512;
        void* args[] = {(void*)&x, (void*)&gamma, (void*)&xf, (void*)&xt, (void*)&c2, (void*)&out};
        hipError_t le = hipLaunchCooperativeKernel(k_fused, dim3(grid), dim3(512),
                                                   args, 0u, stream);
        if (le == hipSuccess) return;
    }

    // fallback: original 3-kernel path
    k_convert<<<dim3(256), dim3(256), 0, stream>>>(x, xf, xt);
    k_pass1 <<<dim3(512), dim3(512), 0, stream>>>(xf, c2);
    k_pass2 <<<dim3(512), dim3(512), 0, stream>>>(xf, xt, c2, x, gamma, out);
}

// Round 3
// 79.648 us; speedup vs baseline: 2.2047x; 2.2047x over previous
//
#include <hip/hip_runtime.h>

// ChannelAttention b=2, n=4096, c=32 fp32.
// S = X X^T (Gram), softmax over j per row i, out[j,c] = sum_i attn[i,j] x[i,c]; out*g + x.
//
// R5 -> R6: cooperative fusion REVERTED (grid.sync() measured ~70us each on
// MI355X: k_fused was 156us at 1.5% MfmaUtil — barrier spin, not compute).
// Back to 3 kernels. New lever: per-block L2 traffic is independent of tile
// width (every block reads all of xf/xt), so doubling tile width and halving
// block count halves total L2 traffic:
//   k1: 32-i tiles, 256 blocks  (was 16-i, 512)  -> 64 MB L2
//   k2: 32-j tiles, 256 blocks  (was 16-j, 512)  -> 128 MB L2
// 256 blocks = 1 block/CU, 8 waves. __launch_bounds__(512,2) -> 256 VGPR room.
// Same math, same accumulation order -> bitwise-identical to the R1 kernel.
//
// MFMA plan (16x16x32 f16, K = c = 32):
//  k0: convert x -> Xf16 [b][n][c] and XT f16 [b][c][n]  (ws)
//  k1: Z_i = sum_j exp(s_ij - 48); store c2[i] = -log2(Z_i) - 48*log2e
//  k2: per 32-j tile: S-MFMA -> attn=exp2(s*log2e + c2[i]) (fp16)
//      -> in-register quad shuffle (8x ds_bpermute + 4x cndmask per 16-j) -> PV-MFMA.

typedef _Float16 half8 __attribute__((ext_vector_type(8)));
typedef _Float16 half4v __attribute__((ext_vector_type(4)));
typedef _Float16 half2v __attribute__((ext_vector_type(2)));
typedef float float4v __attribute__((ext_vector_type(4)));
typedef int int4v __attribute__((ext_vector_type(4)));

#define NN 4096
#define CC 32
#define L2E 1.44269504f
#define SHIFT 48.0f

// ---------------- k0: fp32 -> fp16 row-major + fp16 transposed ----------------
__global__ __launch_bounds__(256) void k_convert(const float* __restrict__ x,
                                                 _Float16* __restrict__ xf,
                                                 _Float16* __restrict__ xt) {
    const int t = blockIdx.x * 256 + threadIdx.x;   // 65536 threads
    const int n  = t & 4095;
    const int cg = (t >> 12) & 7;
    const int b  = t >> 15;
    const int row = (b << 12) | n;
    const float4* src = (const float4*)(x + (size_t)row * CC + cg * 4);
    float4 v = *src;
    _Float16 h0 = (_Float16)v.x, h1 = (_Float16)v.y, h2 = (_Float16)v.z, h3 = (_Float16)v.w;
    *(half4v*)(xf + (size_t)row * CC + cg * 4) = (half4v){h0, h1, h2, h3};
    _Float16* xtb = xt + (size_t)b * CC * NN;
    xtb[(cg * 4 + 0) * NN + n] = h0;   // consecutive lanes -> consecutive n: coalesced
    xtb[(cg * 4 + 1) * NN + n] = h1;
    xtb[(cg * 4 + 2) * NN + n] = h2;
    xtb[(cg * 4 + 3) * NN + n] = h3;
}

// ---------------- k1: per-row shifted sum-of-exp -> c2[i] ----------------
// Block = 512 threads (8 waves), one 32-row i-tile (2 A-frags); each wave covers
// 512 j's, 4 B-tiles/iter, 1-deep prefetch. 256 blocks total.
__global__ __launch_bounds__(512, 2) void k_pass1(const _Float16* __restrict__ xf,
                                                  float* __restrict__ c2out) {
    const int tid = threadIdx.x;
    const int wave = tid >> 6, lane = tid & 63;
    const int quad = lane >> 4, l15 = lane & 15;
    const int b = blockIdx.x >> 7;
    const int i0 = (blockIdx.x & 127) * 32;
    const _Float16* xb = xf + (size_t)b * NN * CC;

    const half8 af0 = *(const half8*)(xb + (size_t)(i0 + l15) * CC + quad * 8);
    const half8 af1 = *(const half8*)(xb + (size_t)(i0 + 16 + l15) * CC + quad * 8);
    const float4v zf = {0.f, 0.f, 0.f, 0.f};
    float z0[4] = {0.f, 0.f, 0.f, 0.f};
    float z1[4] = {0.f, 0.f, 0.f, 0.f};
    const float c2c = -SHIFT * L2E;

    const int jbase = wave * 512;
    half8 b0 = *(const half8*)(xb + (size_t)(jbase + l15) * CC + quad * 8);
    half8 b1 = *(const half8*)(xb + (size_t)(jbase + 16 + l15) * CC + quad * 8);
    half8 b2 = *(const half8*)(xb + (size_t)(jbase + 32 + l15) * CC + quad * 8);
    half8 b3 = *(const half8*)(xb + (size_t)(jbase + 48 + l15) * CC + quad * 8);

    for (int jt = 0; jt < 8; ++jt) {           // 8 iters x 4 tiles x 16 j = 512 j
        const int jn = jbase + ((jt + 1) & 7) * 64;   // wraps on last iter (harmless)
        half8 n0 = *(const half8*)(xb + (size_t)(jn + l15) * CC + quad * 8);
        half8 n1 = *(const half8*)(xb + (size_t)(jn + 16 + l15) * CC + quad * 8);
        half8 n2 = *(const half8*)(xb + (size_t)(jn + 32 + l15) * CC + quad * 8);
        half8 n3 = *(const half8*)(xb + (size_t)(jn + 48 + l15) * CC + quad * 8);

        float4v s00 = __builtin_amdgcn_mfma_f32_16x16x32_f16(af0, b0, zf, 0, 0, 0);
        float4v s01 = __builtin_amdgcn_mfma_f32_16x16x32_f16(af0, b1, zf, 0, 0, 0);
        float4v s02 = __builtin_amdgcn_mfma_f32_16x16x32_f16(af0, b2, zf, 0, 0, 0);
        float4v s03 = __builtin_amdgcn_mfma_f32_16x16x32_f16(af0, b3, zf, 0, 0, 0);
        float4v s10 = __builtin_amdgcn_mfma_f32_16x16x32_f16(af1, b0, zf, 0, 0, 0);
        float4v s11 = __builtin_amdgcn_mfma_f32_16x16x32_f16(af1, b1, zf, 0, 0, 0);
        float4v s12 = __builtin_amdgcn_mfma_f32_16x16x32_f16(af1, b2, zf, 0, 0, 0);
        float4v s13 = __builtin_amdgcn_mfma_f32_16x16x32_f16(af1, b3, zf, 0, 0, 0);
#pragma unroll
        for (int r = 0; r < 4; ++r) {
            z0[r] += __builtin_amdgcn_exp2f(fmaf(s00[r], L2E, c2c));
            z0[r] += __builtin_amdgcn_exp2f(fmaf(s01[r], L2E, c2c));
            z0[r] += __builtin_amdgcn_exp2f(fmaf(s02[r], L2E, c2c));
            z0[r] += __builtin_amdgcn_exp2f(fmaf(s03[r], L2E, c2c));
            z1[r] += __builtin_amdgcn_exp2f(fmaf(s10[r], L2E, c2c));
            z1[r] += __builtin_amdgcn_exp2f(fmaf(s11[r], L2E, c2c));
            z1[r] += __builtin_amdgcn_exp2f(fmaf(s12[r], L2E, c2c));
            z1[r] += __builtin_amdgcn_exp2f(fmaf(s13[r], L2E, c2c));
        }
        b0 = n0; b1 = n1; b2 = n2; b3 = n3;
    }
    // combine over the 16 j-lanes within each quad group
#pragma unroll
    for (int off = 1; off <= 8; off <<= 1) {
#pragma unroll
        for (int r = 0; r < 4; ++r) {
            z0[r] += __shfl_xor(z0[r], off, 64);
            z1[r] += __shfl_xor(z1[r], off, 64);
        }
    }
    __shared__ float zw[8][32];
    if (l15 == 0) {
#pragma unroll
        for (int r = 0; r < 4; ++r) {
            zw[wave][quad * 4 + r]      = z0[r];
            zw[wave][16 + quad * 4 + r] = z1[r];
        }
    }
    __syncthreads();
    if (tid < 32) {
        float zs = 0.f;
#pragma unroll
        for (int w = 0; w < 8; ++w) zs += zw[w][tid];
        c2out[b * NN + i0 + tid] = -(__builtin_amdgcn_logf(zs) + SHIFT * L2E);
    }
}

// ---------------- k2: output pass ----------------
// Block = 512 threads (8 waves), one 32-j tile (2 B-frags); wave w covers i in
// [w*512,(w+1)*512), 32 i per iteration (16 iters). 256 blocks total.
// C->A transpose in registers per 16-j subtile: 8x ds_bpermute + 4x cndmask.
__global__ __launch_bounds__(512, 2) void k_pass2(const _Float16* __restrict__ xf,
                                                  const _Float16* __restrict__ xt,
                                                  const float* __restrict__ c2,
                                                  const float* __restrict__ x,
                                                  const float* __restrict__ gamma,
                                                  float* __restrict__ out) {
    const int tid = threadIdx.x;
    const int wave = tid >> 6, lane = tid & 63;
    const int quad = lane >> 4, l15 = lane & 15;
    const int b = blockIdx.x >> 7;
    const int j0 = (blockIdx.x & 127) * 32;
    const _Float16* xb  = xf + (size_t)b * NN * CC;
    const _Float16* xtb = xt + (size_t)b * CC * NN;
    const float* c2b = c2 + b * NN;

    __shared__ float red[8][32][32];

    // bpermute byte addresses: A0/A1 pull from lane ((q&1)*32 + j15),
    // A2/A3 from lane ((q&1)*32 + 16 + j15). Select p0 (q<2) vs p1 (q>=2) data.
    const int addrLo = (((quad & 1) << 5) + l15) << 2;
    const int addrHi = addrLo + 64;
    const bool lo32 = (lane < 32);

    const half8 bj0 = *(const half8*)(xb + (size_t)(j0 + l15) * CC + quad * 8);
    const half8 bj1 = *(const half8*)(xb + (size_t)(j0 + 16 + l15) * CC + quad * 8);
    const float4v zf = {0.f, 0.f, 0.f, 0.f};
    float4v acc00 = zf, acc01 = zf, acc10 = zf, acc11 = zf;

    const int ibase = wave * 512;
    half8 a0  = *(const half8*)(xb + (size_t)(ibase + l15) * CC + quad * 8);
    half8 a1  = *(const half8*)(xb + (size_t)(ibase + 16 + l15) * CC + quad * 8);
    half8 xb0 = *(const half8*)(xtb + (size_t)l15 * NN + ibase + quad * 8);
    half8 xb1 = *(const half8*)(xtb + (size_t)(l15 + 16) * NN + ibase + quad * 8);
    float4v c20 = *(const float4v*)(c2b + ibase + quad * 4);
    float4v c21 = *(const float4v*)(c2b + ibase + 16 + quad * 4);

    for (int it = 0; it < 16; ++it) {
        const int inx = ibase + ((it + 1) & 15) * 32;   // wraps on last iter
        half8 na0  = *(const half8*)(xb + (size_t)(inx + l15) * CC + quad * 8);
        half8 na1  = *(const half8*)(xb + (size_t)(inx + 16 + l15) * CC + quad * 8);
        half8 nxb0 = *(const half8*)(xtb + (size_t)l15 * NN + inx + quad * 8);
        half8 nxb1 = *(const half8*)(xtb + (size_t)(l15 + 16) * NN + inx + quad * 8);
        float4v nc20 = *(const float4v*)(c2b + inx + quad * 4);
        float4v nc21 = *(const float4v*)(c2b + inx + 16 + quad * 4);

        float4v s00 = __builtin_amdgcn_mfma_f32_16x16x32_f16(a0, bj0, zf, 0, 0, 0);
        float4v s10 = __builtin_amdgcn_mfma_f32_16x16x32_f16(a1, bj0, zf, 0, 0, 0);
        float4v s01 = __builtin_amdgcn_mfma_f32_16x16x32_f16(a0, bj1, zf, 0, 0, 0);
        float4v s11 = __builtin_amdgcn_mfma_f32_16x16x32_f16(a1, bj1, zf, 0, 0, 0);
        float4v e00, e10, e01, e11;
#pragma unroll
        for (int r = 0; r < 4; ++r) {
            e00[r] = __builtin_amdgcn_exp2f(fmaf(s00[r], L2E, c20[r]));
            e10[r] = __builtin_amdgcn_exp2f(fmaf(s10[r], L2E, c21[r]));
            e01[r] = __builtin_amdgcn_exp2f(fmaf(s01[r], L2E, c20[r]));
            e11[r] = __builtin_amdgcn_exp2f(fmaf(s11[r], L2E, c21[r]));
        }
        // ---- subtile 0 (j = j0..j0+15) transpose ----
        {
            const int d0 = __builtin_bit_cast(int, (half2v)__builtin_amdgcn_cvt_pkrtz(e00[0], e00[1]));
            const int d1 = __builtin_bit_cast(int, (half2v)__builtin_amdgcn_cvt_pkrtz(e00[2], e00[3]));
            const int d2 = __builtin_bit_cast(int, (half2v)__builtin_amdgcn_cvt_pkrtz(e10[0], e10[1]));
            const int d3 = __builtin_bit_cast(int, (half2v)__builtin_amdgcn_cvt_pkrtz(e10[2], e10[3]));
            const int q0 = __builtin_amdgcn_ds_bpermute(addrLo, d0);
            const int q1 = __builtin_amdgcn_ds_bpermute(addrLo, d1);
            const int q2 = __builtin_amdgcn_ds_bpermute(addrHi, d0);
            const int q3 = __builtin_amdgcn_ds_bpermute(addrHi, d1);
            const int q4 = __builtin_amdgcn_ds_bpermute(addrLo, d2);
            const int q5 = __builtin_amdgcn_ds_bpermute(addrLo, d3);
            const int q6 = __builtin_amdgcn_ds_bpermute(addrHi, d2);
            const int q7 = __builtin_amdgcn_ds_bpermute(addrHi, d3);
            int4v ai;
            ai[0] = lo32 ? q0 : q4;
            ai[1] = lo32 ? q1 : q5;
            ai[2] = lo32 ? q2 : q6;
            ai[3] = lo32 ? q3 : q7;
            const half8 a2 = __builtin_bit_cast(half8, ai);   // P^T[j=j0+l15][i32]
            acc00 = __builtin_amdgcn_mfma_f32_16x16x32_f16(a2, xb0, acc00, 0, 0, 0);
            acc01 = __builtin_amdgcn_mfma_f32_16x16x32_f16(a2, xb1, acc01, 0, 0, 0);
        }
        // ---- subtile 1 (j = j0+16..j0+31) transpose ----
        {
            const int d0 = __builtin_bit_cast(int, (half2v)__builtin_amdgcn_cvt_pkrtz(e01[0], e01[1]));
            const int d1 = __builtin_bit_cast(int, (half2v)__builtin_amdgcn_cvt_pkrtz(e01[2], e01[3]));
            const int d2 = __builtin_bit_cast(int, (half2v)__builtin_amdgcn_cvt_pkrtz(e11[0], e11[1]));
            const int d3 = __builtin_bit_cast(int, (half2v)__builtin_amdgcn_cvt_pkrtz(e11[2], e11[3]));
            const int q0 = __builtin_amdgcn_ds_bpermute(addrLo, d0);
            const int q1 = __builtin_amdgcn_ds_bpermute(addrLo, d1);
            const int q2 = __builtin_amdgcn_ds_bpermute(addrHi, d0);
            const int q3 = __builtin_amdgcn_ds_bpermute(addrHi, d1);
            const int q4 = __builtin_amdgcn_ds_bpermute(addrLo, d2);
            const int q5 = __builtin_amdgcn_ds_bpermute(addrLo, d3);
            const int q6 = __builtin_amdgcn_ds_bpermute(addrHi, d2);
            const int q7 = __builtin_amdgcn_ds_bpermute(addrHi, d3);
            int4v ai;
            ai[0] = lo32 ? q0 : q4;
            ai[1] = lo32 ? q1 : q5;
            ai[2] = lo32 ? q2 : q6;
            ai[3] = lo32 ? q3 : q7;
            const half8 a2 = __builtin_bit_cast(half8, ai);   // P^T[j=j0+16+l15][i32]
            acc10 = __builtin_amdgcn_mfma_f32_16x16x32_f16(a2, xb0, acc10, 0, 0, 0);
            acc11 = __builtin_amdgcn_mfma_f32_16x16x32_f16(a2, xb1, acc11, 0, 0, 0);
        }

        a0 = na0; a1 = na1; xb0 = nxb0; xb1 = nxb1; c20 = nc20; c21 = nc21;
    }

    // block reduction across the 8 waves
#pragma unroll
    for (int r = 0; r < 4; ++r) {
        red[wave][quad * 4 + r][l15]           = acc00[r];
        red[wave][quad * 4 + r][l15 + 16]      = acc01[r];
        red[wave][16 + quad * 4 + r][l15]      = acc10[r];
        red[wave][16 + quad * 4 + r][l15 + 16] = acc11[r];
    }
    __syncthreads();
    {
        const int jj = tid >> 5, c = tid & 31;   // 512 threads: 16 j x 32 c, twice
        const float g = gamma[0];
#pragma unroll
        for (int h = 0; h < 2; ++h) {
            const int j = jj + h * 16;
            float s = 0.f;
#pragma unroll
            for (int w = 0; w < 8; ++w) s += red[w][j][c];
            const size_t o = (size_t)(b * NN + j0 + j) * CC + c;
            out[o] = fmaf(g, s, x[o]);
        }
    }
}

extern "C" void kernel_launch(void* const* d_in, const int* in_sizes, int n_in,
                              void* d_out, int out_size, void* d_ws, size_t ws_size,
                              hipStream_t stream) {
    const float* x     = (const float*)d_in[0];
    const float* gamma = (const float*)d_in[1];
    float* out = (float*)d_out;

    // ws layout: Xf16 (512 KB) | XT f16 (512 KB) | c2 fp32 (32 KB)
    _Float16* xf = (_Float16*)d_ws;
    _Float16* xt = xf + (size_t)2 * NN * CC;
    float*    c2 = (float*)(xt + (size_t)2 * CC * NN);

    k_convert<<<dim3(256), dim3(256), 0, stream>>>(x, xf, xt);
    k_pass1 <<<dim3(256), dim3(512), 0, stream>>>(xf, c2);
    k_pass2 <<<dim3(256), dim3(512), 0, stream>>>(xf, xt, c2, x, gamma, out);
}